// Round 7
// baseline (1543.363 us; speedup 1.0000x reference)
//
#include <hip/hip_runtime.h>
#include <math.h>

#define N_ROWS 100000
#define MUL_IN 256
#define MUL_H  64
#define RPW    8                         // rows per wave
#define NWAVES 4                         // waves per block
#define ROWS_PER_BLOCK (RPW * NWAVES)    // 32 -> 3125 blocks exactly
#define KM     32                        // m-values per chunk
#define NCHUNK (MUL_IN / KM)             // 8
#define LDS_ROW_F 128                    // per row per chunk: 32 xs + 96 xv floats (512 B)

__device__ __forceinline__ float silu_f(float v) {
    return v * (1.0f / (1.0f + __expf(-v)));
}

__global__ __launch_bounds__(NWAVES * 64)
void ndr_fp32_kernel(const float* __restrict__ x,
                     const float* __restrict__ w1_s,
                     const float* __restrict__ w1_v,
                     const float* __restrict__ w2_s,
                     const float* __restrict__ w2_v,
                     float* __restrict__ out)
{
    // 32 rows x 512 B = 16 KB; each wave touches only its own 8 rows -> no barriers
    __shared__ float lds[ROWS_PER_BLOCK * LDS_ROW_F];

    const int lane = threadIdx.x & 63;
    const int w    = threadIdx.x >> 6;
    const int sub  = lane >> 5;          // 0/1: which of the 2 rows this half-wave stages
    const int lw   = lane & 31;
    const long long gRow0 = (long long)blockIdx.x * ROWS_PER_BLOCK;

    float acc_s0[RPW] = {}, acc_s1[RPW] = {};
    float acc_v0[RPW] = {}, acc_v1[RPW] = {}, acc_v2[RPW] = {};

    // Staging map (per chunk, per wave): 4 instrs, each covers 2 rows (64 lanes x 16 B = 1 KB).
    // lw<8  : xs slice  (32 floats)  src fidx = m0 + lw*4        dst fidx = lw*4
    // lw>=8 : xv slice  (96 floats)  src fidx = 256+3*m0+(lw-8)*4 dst fidx = 32+(lw-8)*4
    const bool isXs = (lw < 8);
    const int  dstF = isXs ? (lw * 4) : (32 + (lw - 8) * 4);

    float4 pf[4];
    {   // prefetch chunk 0
        const int srcF = isXs ? (lw * 4) : (256 + (lw - 8) * 4);
        #pragma unroll
        for (int t = 0; t < 4; ++t) {
            int row = w * RPW + 2 * t + sub;
            pf[t] = *(const float4*)(x + (gRow0 + row) * 1024 + srcF);
        }
    }

    #pragma unroll 1
    for (int c = 0; c < NCHUNK; ++c) {
        // commit staged registers to this wave's private LDS rows (full-stripe, conflict-free)
        #pragma unroll
        for (int t = 0; t < 4; ++t) {
            int row = w * RPW + 2 * t + sub;
            *(float4*)(lds + row * LDS_ROW_F + dstF) = pf[t];
        }
        // prefetch next chunk into registers; HBM latency hides under this chunk's FMAs
        if (c + 1 < NCHUNK) {
            const int m0n = (c + 1) * KM;
            const int srcF = isXs ? (m0n + lw * 4) : (256 + 3 * m0n + (lw - 8) * 4);
            #pragma unroll
            for (int t = 0; t < 4; ++t) {
                int row = w * RPW + 2 * t + sub;
                pf[t] = *(const float4*)(x + (gRow0 + row) * 1024 + srcF);
            }
        }

        const int m0 = c * KM;
        const float* ldsw = lds + w * RPW * LDS_ROW_F;

        #pragma unroll
        for (int t = 0; t < KM / 4; ++t) {
            // lane-indexed weight loads: coalesced, L1-resident (24 KB working set/chunk)
            float ws0[4], ws1[4], wv[4];
            #pragma unroll
            for (int u = 0; u < 4; ++u) {
                int m = m0 + 4 * t + u;
                ws0[u] = w1_s[m * 128 + lane];
                ws1[u] = w1_s[m * 128 + 64 + lane];
                wv[u]  = w1_v[m * 64 + lane];
            }
            #pragma unroll
            for (int r = 0; r < RPW; ++r) {
                const float* xr = ldsw + r * LDS_ROW_F;
                // uniform-address LDS reads -> broadcast, conflict-free, imm offsets
                float4 a  = *(const float4*)(xr + 4 * t);            // xs[m0+4t .. +3]
                float4 b0 = *(const float4*)(xr + 32 + 12 * t);      // xv flat 12t..
                float4 b1 = *(const float4*)(xr + 32 + 12 * t + 4);
                float4 b2 = *(const float4*)(xr + 32 + 12 * t + 8);

                acc_s0[r] = fmaf(a.x, ws0[0], acc_s0[r]);
                acc_s0[r] = fmaf(a.y, ws0[1], acc_s0[r]);
                acc_s0[r] = fmaf(a.z, ws0[2], acc_s0[r]);
                acc_s0[r] = fmaf(a.w, ws0[3], acc_s0[r]);

                acc_s1[r] = fmaf(a.x, ws1[0], acc_s1[r]);
                acc_s1[r] = fmaf(a.y, ws1[1], acc_s1[r]);
                acc_s1[r] = fmaf(a.z, ws1[2], acc_s1[r]);
                acc_s1[r] = fmaf(a.w, ws1[3], acc_s1[r]);

                acc_v0[r] = fmaf(b0.x, wv[0], acc_v0[r]);   // t0 i0
                acc_v1[r] = fmaf(b0.y, wv[0], acc_v1[r]);   // t0 i1
                acc_v2[r] = fmaf(b0.z, wv[0], acc_v2[r]);   // t0 i2
                acc_v0[r] = fmaf(b0.w, wv[1], acc_v0[r]);   // t1 i0
                acc_v1[r] = fmaf(b1.x, wv[1], acc_v1[r]);   // t1 i1
                acc_v2[r] = fmaf(b1.y, wv[1], acc_v2[r]);   // t1 i2
                acc_v0[r] = fmaf(b1.z, wv[2], acc_v0[r]);   // t2 i0
                acc_v1[r] = fmaf(b1.w, wv[2], acc_v1[r]);   // t2 i1
                acc_v2[r] = fmaf(b2.x, wv[2], acc_v2[r]);   // t2 i2
                acc_v0[r] = fmaf(b2.y, wv[3], acc_v0[r]);   // t3 i0
                acc_v1[r] = fmaf(b2.z, wv[3], acc_v1[r]);   // t3 i1
                acc_v2[r] = fmaf(b2.w, wv[3], acc_v2[r]);   // t3 i2
            }
        }
    }

    // epilogue: silu-gate + second layer (length-64 contraction = wave butterfly)
    const float inv_in = 0.0625f;   // 1/sqrt(256)
    const float inv_h  = 0.125f;    // 1/sqrt(64)
    const float w2sv = w2_s[lane];
    const float w2vv = w2_v[lane];

    #pragma unroll
    for (int r = 0; r < RPW; ++r) {
        float hs = acc_s0[r] * inv_in;
        float hg = acc_s1[r] * inv_in;
        float g  = silu_f(hg);
        float v0 = silu_f(hs) * w2sv;
        float v1 = g * (acc_v0[r] * inv_in) * w2vv;
        float v2 = g * (acc_v1[r] * inv_in) * w2vv;
        float v3 = g * (acc_v2[r] * inv_in) * w2vv;

        #pragma unroll
        for (int off = 32; off; off >>= 1) {
            v0 += __shfl_xor(v0, off, 64);
            v1 += __shfl_xor(v1, off, 64);
            v2 += __shfl_xor(v2, off, 64);
            v3 += __shfl_xor(v3, off, 64);
        }
        if (lane == 0) {
            float4 o = make_float4(v0 * inv_h, v1 * inv_h, v2 * inv_h, v3 * inv_h);
            *(float4*)(out + (gRow0 + w * RPW + r) * 4) = o;
        }
    }
}

extern "C" void kernel_launch(void* const* d_in, const int* in_sizes, int n_in,
                              void* d_out, int out_size, void* d_ws, size_t ws_size,
                              hipStream_t stream) {
    const float* x    = (const float*)d_in[0];
    const float* w1_s = (const float*)d_in[1];
    const float* w1_v = (const float*)d_in[2];
    const float* w2_s = (const float*)d_in[3];
    const float* w2_v = (const float*)d_in[4];
    float* out = (float*)d_out;

    int blocks = N_ROWS / ROWS_PER_BLOCK;  // 3125 exactly, no tail
    ndr_fp32_kernel<<<blocks, NWAVES * 64, 0, stream>>>(x, w1_s, w1_v, w2_s, w2_v, out);
}

// Round 8
// 403.856 us; speedup vs baseline: 3.8216x; 3.8216x over previous
//
#include <hip/hip_runtime.h>
#include <math.h>

#define N_ROWS 100000
#define MUL_IN 256
#define MUL_H  64
#define RPW    8                         // rows per wave
#define NWAVES 4                         // waves per block
#define ROWS_PER_BLOCK (RPW * NWAVES)    // 32 -> 3125 blocks exactly
#define KM     32                        // m-values per chunk
#define NCHUNK (MUL_IN / KM)             // 8

__device__ __forceinline__ float silu_f(float v) {
    return v * (1.0f / (1.0f + __expf(-v)));
}

// async global->LDS: per-lane global src, wave-uniform LDS base + lane*16B dest
__device__ __forceinline__ void stage16(const float* g, float* l) {
    __builtin_amdgcn_global_load_lds(
        (const __attribute__((address_space(1))) unsigned int*)g,
        (__attribute__((address_space(3))) unsigned int*)l,
        16, 0, 0);
}

__global__ __launch_bounds__(256, 4)   // min 4 waves/EU -> VGPR cap 128, no spill bloat
void ndr_fp32_kernel(const float* __restrict__ x,
                     const float* __restrict__ w1_s,
                     const float* __restrict__ w1_v,
                     const float* __restrict__ w2_s,
                     const float* __restrict__ w2_v,
                     float* __restrict__ out)
{
    // double-buffered, wave-private: 2 bufs x 4 waves x (8 rows x 128 floats) = 32 KB
    __shared__ float lds[2][NWAVES][RPW * 128];

    const int lane = threadIdx.x & 63;
    const int w    = threadIdx.x >> 6;
    const int sub  = lane >> 5;          // which of the 2 rows this instr's half covers
    const int lw   = lane & 31;
    const long long gRow0 = (long long)blockIdx.x * ROWS_PER_BLOCK + w * RPW;

    float acc_s0[RPW] = {}, acc_s1[RPW] = {};
    float acc_v0[RPW] = {}, acc_v1[RPW] = {}, acc_v2[RPW] = {};

    // Per-lane global source offset within a row, for chunk starting at m0:
    //   lanes lw<8  : xs slice, float idx m0 + lw*4          (32 floats)
    //   lanes lw>=8 : xv slice, float idx 256 + 3*m0 + (lw-8)*4  (96 floats)
    // LDS dest (linear, lane*16B from base): row-major [row][128]: xs at 0..31, xv at 32..127.
    const bool isXs   = (lw < 8);
    const int  baseOff = isXs ? (lw * 4) : (256 + (lw - 8) * 4);
    const int  offMul  = isXs ? 1 : 3;   // chunk advance: m0 for xs, 3*m0 for xv

    // stage chunk 0 into buf 0 (4 instrs: t covers rows 2t, 2t+1)
    #pragma unroll
    for (int t = 0; t < 4; ++t) {
        const float* g = x + (gRow0 + 2 * t + sub) * 1024 + baseOff;
        stage16(g, &lds[0][w][t * 256]);
    }

    #pragma unroll 1
    for (int c = 0; c < NCHUNK; ++c) {
        if (c + 1 < NCHUNK) {
            // issue next-chunk staging, then wait with count 4: everything older
            // (= this chunk's staging + all prior weight loads) has landed.
            const int m0n = (c + 1) * KM;
            #pragma unroll
            for (int t = 0; t < 4; ++t) {
                const float* g = x + (gRow0 + 2 * t + sub) * 1024 + baseOff + offMul * m0n;
                stage16(g, &lds[(c + 1) & 1][w][t * 256]);
            }
            asm volatile("s_waitcnt vmcnt(4)" ::: "memory");
        } else {
            asm volatile("s_waitcnt vmcnt(0)" ::: "memory");
        }

        const float* xw = &lds[c & 1][w][0];
        const int m0 = c * KM;

        #pragma unroll 2                 // cap live weight regs at 2x12
        for (int t = 0; t < KM / 4; ++t) {
            float ws0[4], ws1[4], wv[4]; // lane-indexed, coalesced, L1/L2-resident
            #pragma unroll
            for (int u = 0; u < 4; ++u) {
                int m = m0 + 4 * t + u;
                ws0[u] = w1_s[m * 128 + lane];
                ws1[u] = w1_s[m * 128 + 64 + lane];
                wv[u]  = w1_v[m * 64 + lane];
            }
            #pragma unroll
            for (int r = 0; r < RPW; ++r) {
                const float* xr = xw + r * 128;
                // uniform-address LDS reads: broadcast, conflict-free, imm offsets
                float4 a  = *(const float4*)(xr + 4 * t);           // xs[4t..4t+3]
                float4 b0 = *(const float4*)(xr + 32 + 12 * t);     // xv flat 12t..
                float4 b1 = *(const float4*)(xr + 32 + 12 * t + 4);
                float4 b2 = *(const float4*)(xr + 32 + 12 * t + 8);

                acc_s0[r] = fmaf(a.x, ws0[0], acc_s0[r]);
                acc_s0[r] = fmaf(a.y, ws0[1], acc_s0[r]);
                acc_s0[r] = fmaf(a.z, ws0[2], acc_s0[r]);
                acc_s0[r] = fmaf(a.w, ws0[3], acc_s0[r]);

                acc_s1[r] = fmaf(a.x, ws1[0], acc_s1[r]);
                acc_s1[r] = fmaf(a.y, ws1[1], acc_s1[r]);
                acc_s1[r] = fmaf(a.z, ws1[2], acc_s1[r]);
                acc_s1[r] = fmaf(a.w, ws1[3], acc_s1[r]);

                acc_v0[r] = fmaf(b0.x, wv[0], acc_v0[r]);   // t0 i0
                acc_v1[r] = fmaf(b0.y, wv[0], acc_v1[r]);   // t0 i1
                acc_v2[r] = fmaf(b0.z, wv[0], acc_v2[r]);   // t0 i2
                acc_v0[r] = fmaf(b0.w, wv[1], acc_v0[r]);   // t1 i0
                acc_v1[r] = fmaf(b1.x, wv[1], acc_v1[r]);   // t1 i1
                acc_v2[r] = fmaf(b1.y, wv[1], acc_v2[r]);   // t1 i2
                acc_v0[r] = fmaf(b1.z, wv[2], acc_v0[r]);   // t2 i0
                acc_v1[r] = fmaf(b1.w, wv[2], acc_v1[r]);   // t2 i1
                acc_v2[r] = fmaf(b2.x, wv[2], acc_v2[r]);   // t2 i2
                acc_v0[r] = fmaf(b2.y, wv[3], acc_v0[r]);   // t3 i0
                acc_v1[r] = fmaf(b2.z, wv[3], acc_v1[r]);   // t3 i1
                acc_v2[r] = fmaf(b2.w, wv[3], acc_v2[r]);   // t3 i2
            }
        }
    }

    // epilogue: silu-gate + second layer (length-64 contraction = wave butterfly)
    const float inv_in = 0.0625f;   // 1/sqrt(256)
    const float inv_h  = 0.125f;    // 1/sqrt(64)
    const float w2sv = w2_s[lane];
    const float w2vv = w2_v[lane];

    #pragma unroll
    for (int r = 0; r < RPW; ++r) {
        float hs = acc_s0[r] * inv_in;
        float hg = acc_s1[r] * inv_in;
        float g  = silu_f(hg);
        float v0 = silu_f(hs) * w2sv;
        float v1 = g * (acc_v0[r] * inv_in) * w2vv;
        float v2 = g * (acc_v1[r] * inv_in) * w2vv;
        float v3 = g * (acc_v2[r] * inv_in) * w2vv;

        #pragma unroll
        for (int off = 32; off; off >>= 1) {
            v0 += __shfl_xor(v0, off, 64);
            v1 += __shfl_xor(v1, off, 64);
            v2 += __shfl_xor(v2, off, 64);
            v3 += __shfl_xor(v3, off, 64);
        }
        if (lane == 0) {
            float4 o = make_float4(v0 * inv_h, v1 * inv_h, v2 * inv_h, v3 * inv_h);
            *(float4*)(out + (gRow0 + r) * 4) = o;
        }
    }
}

extern "C" void kernel_launch(void* const* d_in, const int* in_sizes, int n_in,
                              void* d_out, int out_size, void* d_ws, size_t ws_size,
                              hipStream_t stream) {
    const float* x    = (const float*)d_in[0];
    const float* w1_s = (const float*)d_in[1];
    const float* w1_v = (const float*)d_in[2];
    const float* w2_s = (const float*)d_in[3];
    const float* w2_v = (const float*)d_in[4];
    float* out = (float*)d_out;

    int blocks = N_ROWS / ROWS_PER_BLOCK;  // 3125 exactly, no tail
    ndr_fp32_kernel<<<blocks, NWAVES * 64, 0, stream>>>(x, w1_s, w1_v, w2_s, w2_v, out);
}

// Round 9
// 222.391 us; speedup vs baseline: 6.9399x; 1.8160x over previous
//
#include <hip/hip_runtime.h>
#include <hip/hip_bf16.h>
#include <math.h>

#define N_ROWS  100000
#define NT_ROW  6250            // 16-row MFMA tiles, exact
#define WT_K    256

typedef __attribute__((ext_vector_type(8))) short bf16x8;   // 4 VGPR A/B frag
typedef __attribute__((ext_vector_type(4))) float f32x4;    // C/D frag

__device__ __forceinline__ float silu_f(float v) {
    return v * (1.0f / (1.0f + __expf(-v)));
}
__device__ __forceinline__ short f2bf(float f) {
    union { __hip_bfloat16 h; short s; } u;
    u.h = __float2bfloat16(f);          // RNE convert (v_cvt pattern)
    return u.s;
}

// ---- pre-kernel: wT[col][k] bf16, col = tile*16 + c2 -----------------------
// tiles 0-7: w1_s cols 0-127 (scalars+gates); tiles 8-11/12-15/16-19: w1_v
// (same content replicated for the 3 xv components; A-fragment differs).
__global__ __launch_bounds__(64)
void prep_wT(const float* __restrict__ w1_s, const float* __restrict__ w1_v,
             unsigned short* __restrict__ wT)
{
    const int col = blockIdx.x;              // 0..319
    const int t = col >> 4, c2 = col & 15;
    const int k0 = threadIdx.x * 4;          // 4 consecutive k per lane
    const float* src   = (t < 8) ? w1_s : w1_v;
    const int    strd  = (t < 8) ? 128 : 64;
    const int    scol  = (t < 8) ? (t * 16 + c2) : (((t - 8) & 3) * 16 + c2);
    ushort4 o;
    o.x = (unsigned short)f2bf(src[(k0 + 0) * strd + scol]);
    o.y = (unsigned short)f2bf(src[(k0 + 1) * strd + scol]);
    o.z = (unsigned short)f2bf(src[(k0 + 2) * strd + scol]);
    o.w = (unsigned short)f2bf(src[(k0 + 3) * strd + scol]);
    *(ushort4*)(wT + (size_t)col * WT_K + k0) = o;
}

// ---- main kernel: 1 wave = 16 rows x 320 cols, K=256, no LDS ---------------
__global__ __launch_bounds__(256, 3)
void ndr_mfma_kernel(const float* __restrict__ x,
                     const unsigned short* __restrict__ wT,
                     const float* __restrict__ w2_s,
                     const float* __restrict__ w2_v,
                     float* __restrict__ out)
{
    const int lane = threadIdx.x & 63;
    const int wid  = threadIdx.x >> 6;
    const int rt   = blockIdx.x * 4 + wid;
    if (rt >= NT_ROW) return;                // no barriers in kernel -> safe
    const int l15 = lane & 15, lq = lane >> 4;     // lq = 0..3 (k-quarter)
    const long long n0 = (long long)rt * 16;
    const float* xrow = x + (n0 + l15) * 1024;     // this lane's A-row

    f32x4 acc[20];
    #pragma unroll
    for (int t = 0; t < 20; ++t) acc[t] = (f32x4){0.f, 0.f, 0.f, 0.f};

    // per-lane B base: element (l15*256 + lq*8), bytes l15*512 + lq*16
    const char* wbase = (const char*)wT + l15 * 512 + lq * 16;

    #pragma unroll 1
    for (int p = 0; p < 8; ++p) {            // K-pass: k = 32p .. 32p+31
        // A data, coalesced from global (x read exactly once per kernel):
        // xs: 8 floats at 32p + 8*lq ; xv: 24 floats at 256 + 96p + 24*lq
        float4 s0 = *(const float4*)(xrow + 32 * p + 8 * lq);
        float4 s1 = *(const float4*)(xrow + 32 * p + 8 * lq + 4);
        float4 v0 = *(const float4*)(xrow + 256 + 96 * p + 24 * lq);
        float4 v1 = *(const float4*)(xrow + 256 + 96 * p + 24 * lq + 4);
        float4 v2 = *(const float4*)(xrow + 256 + 96 * p + 24 * lq + 8);
        float4 v3 = *(const float4*)(xrow + 256 + 96 * p + 24 * lq + 12);
        float4 v4 = *(const float4*)(xrow + 256 + 96 * p + 24 * lq + 16);
        float4 v5 = *(const float4*)(xrow + 256 + 96 * p + 24 * lq + 20);

        const float xs[8]  = {s0.x, s0.y, s0.z, s0.w, s1.x, s1.y, s1.z, s1.w};
        const float xv[24] = {v0.x, v0.y, v0.z, v0.w, v1.x, v1.y, v1.z, v1.w,
                              v2.x, v2.y, v2.z, v2.w, v3.x, v3.y, v3.z, v3.w,
                              v4.x, v4.y, v4.z, v4.w, v5.x, v5.y, v5.z, v5.w};
        bf16x8 a_s, a_v0, a_v1, a_v2;        // A[row=l15][k=32p+8lq+e]
        #pragma unroll
        for (int e = 0; e < 8; ++e) {
            a_s[e]  = f2bf(xs[e]);
            a_v0[e] = f2bf(xv[3 * e + 0]);   // xv[n][m][i] = x[n][256+3m+i]
            a_v1[e] = f2bf(xv[3 * e + 1]);
            a_v2[e] = f2bf(xv[3 * e + 2]);
        }

        const char* wp = wbase + p * 64;     // k-advance: 32 elems * 2 B
        #pragma unroll
        for (int t = 0; t < 20; ++t) {
            bf16x8 b = *(const bf16x8*)(wp + (size_t)t * 8192);  // col-tile t
            const bf16x8 a = (t < 8) ? a_s : (t < 12) ? a_v0
                            : (t < 16) ? a_v1 : a_v2;
            acc[t] = __builtin_amdgcn_mfma_f32_16x16x32_bf16(a, b, acc[t], 0, 0, 0);
        }
    }

    // ---- epilogue: silu-gate + layer 2 in fp32 -----------------------------
    // C/D layout: col = lane&15, row = lq*4 + reg  (m89-verified)
    const float inv_in = 0.0625f, inv_h = 0.125f;
    float w2sv[4], w2vv[4];
    #pragma unroll
    for (int u = 0; u < 4; ++u) {
        w2sv[u] = w2_s[u * 16 + l15];
        w2vv[u] = w2_v[u * 16 + l15];
    }
    #pragma unroll
    for (int j = 0; j < 4; ++j) {            // 4 rows per lane-quarter
        float ps = 0.f, pv0 = 0.f, pv1 = 0.f, pv2 = 0.f;
        #pragma unroll
        for (int u = 0; u < 4; ++u) {        // hidden cols u*16 + l15
            float hs = acc[u][j]     * inv_in;   // scalars (cols 0-63)
            float hg = acc[4 + u][j] * inv_in;   // gates   (cols 64-127)
            float gg = silu_f(hg);
            ps  += silu_f(hs) * w2sv[u];
            pv0 += gg * (acc[8  + u][j] * inv_in) * w2vv[u];
            pv1 += gg * (acc[12 + u][j] * inv_in) * w2vv[u];
            pv2 += gg * (acc[16 + u][j] * inv_in) * w2vv[u];
        }
        #pragma unroll
        for (int off = 1; off <= 8; off <<= 1) {   // reduce over l15 group
            ps  += __shfl_xor(ps,  off, 64);
            pv0 += __shfl_xor(pv0, off, 64);
            pv1 += __shfl_xor(pv1, off, 64);
            pv2 += __shfl_xor(pv2, off, 64);
        }
        if (l15 == 0) {
            long long n = n0 + lq * 4 + j;
            *(float4*)(out + n * 4) =
                make_float4(ps * inv_h, pv0 * inv_h, pv1 * inv_h, pv2 * inv_h);
        }
    }
}

extern "C" void kernel_launch(void* const* d_in, const int* in_sizes, int n_in,
                              void* d_out, int out_size, void* d_ws, size_t ws_size,
                              hipStream_t stream) {
    const float* x    = (const float*)d_in[0];
    const float* w1_s = (const float*)d_in[1];
    const float* w1_v = (const float*)d_in[2];
    const float* w2_s = (const float*)d_in[3];
    const float* w2_v = (const float*)d_in[4];
    float* out = (float*)d_out;
    unsigned short* wT = (unsigned short*)d_ws;       // 320*256*2 = 160 KB

    prep_wT<<<320, 64, 0, stream>>>(w1_s, w1_v, wT);
    int blocks = (NT_ROW + 3) / 4;                    // 1563; tail waves exit
    ndr_mfma_kernel<<<blocks, 256, 0, stream>>>(x, wT, w2_s, w2_v, out);
}

// Round 10
// 186.401 us; speedup vs baseline: 8.2798x; 1.1931x over previous
//
#include <hip/hip_runtime.h>
#include <hip/hip_bf16.h>
#include <math.h>

#define N_ROWS  100000
#define NT_ROW  6250            // 16-row MFMA tiles, exact
#define WT_K    256

typedef __attribute__((ext_vector_type(8))) short bf16x8;   // 4 VGPR A/B frag
typedef __attribute__((ext_vector_type(4))) float f32x4;    // C/D frag

__device__ __forceinline__ float silu_f(float v) {
    return v * (1.0f / (1.0f + __expf(-v)));
}
__device__ __forceinline__ short f2bf(float f) {
    union { __hip_bfloat16 h; short s; } u;
    u.h = __float2bfloat16(f);          // RNE convert
    return u.s;
}

// ---- pre-kernel: fragment-packed weights ----------------------------------
// wTf[(t*8+p)*1024 B + lane*16 B] = B-fragment for col-tile t, K-pass p:
//   lane = lq*16 + l15 holds bf16 of W[k = 32p + 8lq + e][col(t, l15)], e=0..7
// tiles 0-7: w1_s cols 0-127; tiles 8-11/12-15/16-19: w1_v cols (replicated
// for the 3 xv components; only the A-fragment differs).
__global__ __launch_bounds__(64)
void prep_wT(const float* __restrict__ w1_s, const float* __restrict__ w1_v,
             unsigned short* __restrict__ wTf)
{
    const int tp = blockIdx.x;               // 0..159 = t*8 + p
    const int t = tp >> 3, p = tp & 7;
    const int lane = threadIdx.x;            // 0..63
    const int l15 = lane & 15, lq = lane >> 4;
    const float* src  = (t < 8) ? w1_s : w1_v;
    const int    strd = (t < 8) ? 128 : 64;
    const int    scol = (t < 8) ? (t * 16 + l15) : (((t - 8) & 3) * 16 + l15);
    const int    k0   = 32 * p + 8 * lq;
    unsigned short o[8];
    #pragma unroll
    for (int e = 0; e < 8; ++e)
        o[e] = (unsigned short)f2bf(src[(k0 + e) * strd + scol]);
    *(ushort4*)(wTf + (size_t)tp * 512 + lane * 8)     = make_ushort4(o[0], o[1], o[2], o[3]);
    *(ushort4*)(wTf + (size_t)tp * 512 + lane * 8 + 4) = make_ushort4(o[4], o[5], o[6], o[7]);
}

// ---- main kernel: 1 wave = 16 rows x 320 cols, K=256, no LDS ---------------
__global__ __launch_bounds__(256, 2)
void ndr_mfma_kernel(const float* __restrict__ x,
                     const unsigned short* __restrict__ wTf,
                     const float* __restrict__ w2_s,
                     const float* __restrict__ w2_v,
                     float* __restrict__ out)
{
    const int lane = threadIdx.x & 63;
    const int wid  = threadIdx.x >> 6;
    const int rt   = blockIdx.x * 4 + wid;
    if (rt >= NT_ROW) return;                // no barriers in kernel -> safe
    const int l15 = lane & 15, lq = lane >> 4;     // lq = 0..3 (k-quarter)
    const long long n0 = (long long)rt * 16;
    const float* xrow = x + (n0 + l15) * 1024;     // this lane's A-row

    f32x4 acc[20];
    #pragma unroll
    for (int t = 0; t < 20; ++t) acc[t] = (f32x4){0.f, 0.f, 0.f, 0.f};

    // fragment-packed B: one fully-coalesced b128 per (tile, pass)
    const char* wbase = (const char*)wTf + lane * 16;

    // ---- 1-ahead x prefetch pipeline ----
    float4 pf[8];
    #pragma unroll
    for (int q = 0; q < 2; ++q) {            // xs: floats 32p + 8lq .. +8
        pf[q] = *(const float4*)(xrow + 8 * lq + 4 * q);
    }
    #pragma unroll
    for (int q = 0; q < 6; ++q) {            // xv: floats 256 + 96p + 24lq ..
        pf[2 + q] = *(const float4*)(xrow + 256 + 24 * lq + 4 * q);
    }

    #pragma unroll 1
    for (int p = 0; p < 8; ++p) {            // K-pass: k = 32p .. 32p+31
        // convert prefetched pass-p data to bf16 A-fragments
        const float xs[8]  = {pf[0].x, pf[0].y, pf[0].z, pf[0].w,
                              pf[1].x, pf[1].y, pf[1].z, pf[1].w};
        const float xv[24] = {pf[2].x, pf[2].y, pf[2].z, pf[2].w,
                              pf[3].x, pf[3].y, pf[3].z, pf[3].w,
                              pf[4].x, pf[4].y, pf[4].z, pf[4].w,
                              pf[5].x, pf[5].y, pf[5].z, pf[5].w,
                              pf[6].x, pf[6].y, pf[6].z, pf[6].w,
                              pf[7].x, pf[7].y, pf[7].z, pf[7].w};
        bf16x8 a_s, a_v0, a_v1, a_v2;        // A[row=l15][k=32p+8lq+e]
        #pragma unroll
        for (int e = 0; e < 8; ++e) {
            a_s[e]  = f2bf(xs[e]);
            a_v0[e] = f2bf(xv[3 * e + 0]);   // xv[n][m][i] = x[n][256+3m+i]
            a_v1[e] = f2bf(xv[3 * e + 1]);
            a_v2[e] = f2bf(xv[3 * e + 2]);
        }

        // issue next pass's x loads; they fly under this pass's B+MFMA
        if (p + 1 < 8) {
            const int pn = p + 1;
            #pragma unroll
            for (int q = 0; q < 2; ++q)
                pf[q] = *(const float4*)(xrow + 32 * pn + 8 * lq + 4 * q);
            #pragma unroll
            for (int q = 0; q < 6; ++q)
                pf[2 + q] = *(const float4*)(xrow + 256 + 96 * pn + 24 * lq + 4 * q);
        }

        const char* wp = wbase + (size_t)p * 1024;   // pass-p fragments
        #pragma unroll
        for (int t = 0; t < 20; ++t) {
            bf16x8 b = *(const bf16x8*)(wp + (size_t)t * 8192);  // 1 KB burst
            const bf16x8 a = (t < 8) ? a_s : (t < 12) ? a_v0
                            : (t < 16) ? a_v1 : a_v2;
            acc[t] = __builtin_amdgcn_mfma_f32_16x16x32_bf16(a, b, acc[t], 0, 0, 0);
        }
    }

    // ---- epilogue: silu-gate + layer 2 in fp32 -----------------------------
    // C/D layout: col = lane&15, row = lq*4 + reg  (m89-verified)
    const float inv_in = 0.0625f, inv_h = 0.125f;
    float w2sv[4], w2vv[4];
    #pragma unroll
    for (int u = 0; u < 4; ++u) {
        w2sv[u] = w2_s[u * 16 + l15];
        w2vv[u] = w2_v[u * 16 + l15];
    }
    #pragma unroll
    for (int j = 0; j < 4; ++j) {            // 4 rows per lane-quarter
        float ps = 0.f, pv0 = 0.f, pv1 = 0.f, pv2 = 0.f;
        #pragma unroll
        for (int u = 0; u < 4; ++u) {        // hidden cols u*16 + l15
            float hs = acc[u][j]     * inv_in;   // scalars (cols 0-63)
            float hg = acc[4 + u][j] * inv_in;   // gates   (cols 64-127)
            float gg = silu_f(hg);
            ps  += silu_f(hs) * w2sv[u];
            pv0 += gg * (acc[8  + u][j] * inv_in) * w2vv[u];
            pv1 += gg * (acc[12 + u][j] * inv_in) * w2vv[u];
            pv2 += gg * (acc[16 + u][j] * inv_in) * w2vv[u];
        }
        #pragma unroll
        for (int off = 1; off <= 8; off <<= 1) {   // reduce over l15 group
            ps  += __shfl_xor(ps,  off, 64);
            pv0 += __shfl_xor(pv0, off, 64);
            pv1 += __shfl_xor(pv1, off, 64);
            pv2 += __shfl_xor(pv2, off, 64);
        }
        if (l15 == 0) {
            long long n = n0 + lq * 4 + j;
            *(float4*)(out + n * 4) =
                make_float4(ps * inv_h, pv0 * inv_h, pv1 * inv_h, pv2 * inv_h);
        }
    }
}

extern "C" void kernel_launch(void* const* d_in, const int* in_sizes, int n_in,
                              void* d_out, int out_size, void* d_ws, size_t ws_size,
                              hipStream_t stream) {
    const float* x    = (const float*)d_in[0];
    const float* w1_s = (const float*)d_in[1];
    const float* w1_v = (const float*)d_in[2];
    const float* w2_s = (const float*)d_in[3];
    const float* w2_v = (const float*)d_in[4];
    float* out = (float*)d_out;
    unsigned short* wTf = (unsigned short*)d_ws;      // 160*512*2 = 160 KB

    prep_wT<<<160, 64, 0, stream>>>(w1_s, w1_v, wTf);
    int blocks = (NT_ROW + 3) / 4;                    // 1563; tail waves exit
    ndr_mfma_kernel<<<blocks, 256, 0, stream>>>(x, wTf, w2_s, w2_v, out);
}

// Round 11
// 109.243 us; speedup vs baseline: 14.1278x; 1.7063x over previous
//
#include <hip/hip_runtime.h>
#include <hip/hip_bf16.h>
#include <math.h>

#define N_ROWS  100000
#define NT_ROW  6250            // 16-row MFMA tiles, exact

typedef __attribute__((ext_vector_type(8))) short bf16x8;   // 4 VGPR A/B frag
typedef __attribute__((ext_vector_type(4))) float f32x4;    // C/D frag

__device__ __forceinline__ float silu_f(float v) {
    return v * (1.0f / (1.0f + __expf(-v)));
}
__device__ __forceinline__ short f2bf(float f) {
    union { __hip_bfloat16 h; short s; } u;
    u.h = __float2bfloat16(f);          // RNE convert
    return u.s;
}
// async global->LDS: per-lane global src, wave-uniform LDS base + lane*16B dest
__device__ __forceinline__ void stage16(const float* g, float* l) {
    __builtin_amdgcn_global_load_lds(
        (const __attribute__((address_space(1))) unsigned int*)g,
        (__attribute__((address_space(3))) unsigned int*)l,
        16, 0, 0);
}

// ---- pre-kernel: fragment-packed weights (unchanged, verified) -------------
// wTf[(t*8+p)*1024 B + lane*16 B] = B-fragment for col-tile t, K-pass p.
__global__ __launch_bounds__(64)
void prep_wT(const float* __restrict__ w1_s, const float* __restrict__ w1_v,
             unsigned short* __restrict__ wTf)
{
    const int tp = blockIdx.x;               // 0..159 = t*8 + p
    const int t = tp >> 3, p = tp & 7;
    const int lane = threadIdx.x;            // 0..63
    const int l15 = lane & 15, lq = lane >> 4;
    const float* src  = (t < 8) ? w1_s : w1_v;
    const int    strd = (t < 8) ? 128 : 64;
    const int    scol = (t < 8) ? (t * 16 + l15) : (((t - 8) & 3) * 16 + l15);
    const int    k0   = 32 * p + 8 * lq;
    unsigned short o[8];
    #pragma unroll
    for (int e = 0; e < 8; ++e)
        o[e] = (unsigned short)f2bf(src[(k0 + e) * strd + scol]);
    *(ushort4*)(wTf + (size_t)tp * 512 + lane * 8)     = make_ushort4(o[0], o[1], o[2], o[3]);
    *(ushort4*)(wTf + (size_t)tp * 512 + lane * 8 + 4) = make_ushort4(o[4], o[5], o[6], o[7]);
}

// ---- main kernel: 1 wave = 16 rows x 320 cols, LDS-staged x ----------------
// LDS per wave per buffer: 16 rows x 32 slots x 16B = 8 KB, slot XOR-swizzled:
// LDS slot (row, S) holds global segment g = S ^ (row&7) of that row's
// pass-slice (seg 0-7 = xs 128B, seg 8-31 = xv 384B). Write side applies the
// inverse permutation on the global source address (global_load_lds dest is
// linear); read side XORs the slot -> both-sides involution (G21).
__global__ __launch_bounds__(256, 2)
void ndr_mfma_kernel(const float* __restrict__ x,
                     const unsigned short* __restrict__ wTf,
                     const float* __restrict__ w2_s,
                     const float* __restrict__ w2_v,
                     float* __restrict__ out)
{
    __shared__ float lds[2][4][2048];        // [buf][wave][16*128 floats] = 64 KB

    const int lane = threadIdx.x & 63;
    const int wid  = threadIdx.x >> 6;
    const int rt   = blockIdx.x * 4 + wid;
    if (rt >= NT_ROW) return;                // no barriers anywhere -> safe
    const int l15 = lane & 15, lq = lane >> 4;
    const long long n0 = (long long)rt * 16;

    // --- staging map (constant across passes) ---
    // instr j covers rows 2j (lanes 0-31), 2j+1 (lanes 32-63); slot = lane&31.
    const int sub = lane >> 5, slot = lane & 31;
    const float* sp[8];                      // per-j global src for pass 0
    int sstep[8];                            // float advance per pass
    #pragma unroll
    for (int j = 0; j < 8; ++j) {
        const int row = 2 * j + sub;
        const int g   = slot ^ (row & 7);    // inverse-swizzled source segment
        const int isxs = (g < 8);
        const int f0  = isxs ? 4 * g : 256 + 4 * (g - 8);
        sstep[j] = isxs ? 32 : 96;
        sp[j] = x + (n0 + row) * 1024 + f0;
    }

    f32x4 acc[20];
    #pragma unroll
    for (int t = 0; t < 20; ++t) acc[t] = (f32x4){0.f, 0.f, 0.f, 0.f};

    const char* wbase = (const char*)wTf + lane * 16;

    // --- prologue: stage pass 0 -> buf0, pass 1 -> buf1 ---
    #pragma unroll
    for (int j = 0; j < 8; ++j) stage16(sp[j],            &lds[0][wid][j * 256]);
    #pragma unroll
    for (int j = 0; j < 8; ++j) stage16(sp[j] + sstep[j], &lds[1][wid][j * 256]);

    const int r7 = l15 & 7;
    const float* rb0 = &lds[0][wid][l15 * 128];
    const float* rb1 = &lds[1][wid][l15 * 128];

    #pragma unroll 1
    for (int p = 0; p < 8; ++p) {
        // buf[p&1] ready when everything older than the newest 8 stages landed
        if (p < 7) asm volatile("s_waitcnt vmcnt(8)" ::: "memory");
        else       asm volatile("s_waitcnt vmcnt(0)" ::: "memory");

        const float* rb = (p & 1) ? rb1 : rb0;
        // xs: segs 2lq, 2lq+1 ; xv: segs 8+6lq..8+6lq+5 (slot = seg ^ r7)
        float4 s0 = *(const float4*)(rb + 4 * (( 2 * lq     ) ^ r7));
        float4 s1 = *(const float4*)(rb + 4 * (( 2 * lq + 1 ) ^ r7));
        float4 v0 = *(const float4*)(rb + 4 * ((8 + 6 * lq + 0) ^ r7));
        float4 v1 = *(const float4*)(rb + 4 * ((8 + 6 * lq + 1) ^ r7));
        float4 v2 = *(const float4*)(rb + 4 * ((8 + 6 * lq + 2) ^ r7));
        float4 v3 = *(const float4*)(rb + 4 * ((8 + 6 * lq + 3) ^ r7));
        float4 v4 = *(const float4*)(rb + 4 * ((8 + 6 * lq + 4) ^ r7));
        float4 v5 = *(const float4*)(rb + 4 * ((8 + 6 * lq + 5) ^ r7));

        const float xs[8]  = {s0.x, s0.y, s0.z, s0.w, s1.x, s1.y, s1.z, s1.w};
        const float xv[24] = {v0.x, v0.y, v0.z, v0.w, v1.x, v1.y, v1.z, v1.w,
                              v2.x, v2.y, v2.z, v2.w, v3.x, v3.y, v3.z, v3.w,
                              v4.x, v4.y, v4.z, v4.w, v5.x, v5.y, v5.z, v5.w};
        bf16x8 a_s, a_v0, a_v1, a_v2;        // A[row=l15][k=32p+8lq+e]
        #pragma unroll
        for (int e = 0; e < 8; ++e) {
            a_s[e]  = f2bf(xs[e]);
            a_v0[e] = f2bf(xv[3 * e + 0]);
            a_v1[e] = f2bf(xv[3 * e + 1]);
            a_v2[e] = f2bf(xv[3 * e + 2]);
        }

        // B loads BEFORE the stage issue, so in-flight stages stay newest in
        // vmcnt order (MFMA waits never drain them).
        bf16x8 bf[20];
        #pragma unroll
        for (int t = 0; t < 20; ++t)
            bf[t] = *(const bf16x8*)(wbase + (size_t)p * 1024 + (size_t)t * 8192);

        // overwrite the just-consumed buffer with pass p+2 (LDS reads fenced)
        if (p + 2 < 8) {
            asm volatile("s_waitcnt lgkmcnt(0)" ::: "memory");
            #pragma unroll
            for (int j = 0; j < 8; ++j)
                stage16(sp[j] + (p + 2) * sstep[j], &lds[p & 1][wid][j * 256]);
        }

        #pragma unroll
        for (int t = 0; t < 20; ++t) {
            const bf16x8 a = (t < 8) ? a_s : (t < 12) ? a_v0
                            : (t < 16) ? a_v1 : a_v2;
            acc[t] = __builtin_amdgcn_mfma_f32_16x16x32_bf16(a, bf[t], acc[t], 0, 0, 0);
        }
    }

    // ---- epilogue: silu-gate + layer 2 in fp32 (unchanged, verified) -------
    const float inv_in = 0.0625f, inv_h = 0.125f;
    float w2sv[4], w2vv[4];
    #pragma unroll
    for (int u = 0; u < 4; ++u) {
        w2sv[u] = w2_s[u * 16 + l15];
        w2vv[u] = w2_v[u * 16 + l15];
    }
    #pragma unroll
    for (int j = 0; j < 4; ++j) {
        float ps = 0.f, pv0 = 0.f, pv1 = 0.f, pv2 = 0.f;
        #pragma unroll
        for (int u = 0; u < 4; ++u) {
            float hs = acc[u][j]     * inv_in;
            float hg = acc[4 + u][j] * inv_in;
            float gg = silu_f(hg);
            ps  += silu_f(hs) * w2sv[u];
            pv0 += gg * (acc[8  + u][j] * inv_in) * w2vv[u];
            pv1 += gg * (acc[12 + u][j] * inv_in) * w2vv[u];
            pv2 += gg * (acc[16 + u][j] * inv_in) * w2vv[u];
        }
        #pragma unroll
        for (int off = 1; off <= 8; off <<= 1) {
            ps  += __shfl_xor(ps,  off, 64);
            pv0 += __shfl_xor(pv0, off, 64);
            pv1 += __shfl_xor(pv1, off, 64);
            pv2 += __shfl_xor(pv2, off, 64);
        }
        if (l15 == 0) {
            long long n = n0 + lq * 4 + j;
            *(float4*)(out + n * 4) =
                make_float4(ps * inv_h, pv0 * inv_h, pv1 * inv_h, pv2 * inv_h);
        }
    }
}

extern "C" void kernel_launch(void* const* d_in, const int* in_sizes, int n_in,
                              void* d_out, int out_size, void* d_ws, size_t ws_size,
                              hipStream_t stream) {
    const float* x    = (const float*)d_in[0];
    const float* w1_s = (const float*)d_in[1];
    const float* w1_v = (const float*)d_in[2];
    const float* w2_s = (const float*)d_in[3];
    const float* w2_v = (const float*)d_in[4];
    float* out = (float*)d_out;
    unsigned short* wTf = (unsigned short*)d_ws;      // 160*512*2 = 160 KB

    prep_wT<<<160, 64, 0, stream>>>(w1_s, w1_v, wTf);
    int blocks = (NT_ROW + 3) / 4;                    // 1563; tail waves exit
    ndr_mfma_kernel<<<blocks, 256, 0, stream>>>(x, wTf, w2_s, w2_v, out);
}